// Round 14
// baseline (1511.063 us; speedup 1.0000x reference)
//
#include <hip/hip_runtime.h>
#include <hip/hip_bf16.h>
#include <hip/hip_fp16.h>
#include <type_traits>
#include <utility>

// FaceModel: N=500000 nodes, E=3000000 edges, F=128. fp32 in/out, f16 internal.
// R14: nontemporal hints to protect L3 residency of gather-reused data.
//  - gather agg stores -> NT (stop the 125MB output stream evicting x rows;
//    x=128MB should be fully L3-resident but FETCH=386MB says it's thrashed)
//  - layer-kernel input loads -> NT (single-read dead streams leave L3 fast,
//    keeping each layer's output resident for its consumer)
// Everything else identical to R13 (1439us; gathers 2x244us are top-2).

#define NROWS 500000
#define NEDGE 3000000
#define NCHUNK ((NROWS + 63) / 64)          // 7813
#define NBKT 489                             // ceil(NROWS/1024)
#define BSTR 16                              // padded int stride (64B)

typedef unsigned short u16;
using short8 = __attribute__((ext_vector_type(8))) short;
using half8  = __attribute__((ext_vector_type(8))) _Float16;
using f32x4  = __attribute__((ext_vector_type(4))) float;

__device__ __forceinline__ u16 f2h_bits(float f) {
  _Float16 h = (_Float16)f;
  return __builtin_bit_cast(u16, h);
}
__device__ __forceinline__ float h2f(u16 b) {
  return (float)__builtin_bit_cast(_Float16, b);
}
__device__ __forceinline__ float eluf(float x) { return x > 0.0f ? x : expm1f(x); }
// nontemporal vector load of 8 u16 (evict-first hint; single-read streams)
__device__ __forceinline__ short8 ldnt8(const u16* p) {
  return __builtin_nontemporal_load(reinterpret_cast<const short8*>(p));
}

// --- f16 packed atomic add with fallback (scatter fallback path only) ------
template <typename T, typename = void> struct HasUnsafeAdd : std::false_type {};
template <typename T>
struct HasUnsafeAdd<T, std::void_t<decltype(unsafeAtomicAdd(
    std::declval<T*>(), std::declval<T>()))>> : std::true_type {};
template <bool HAS> struct AtomAdd;
template <> struct AtomAdd<true> {
  template <class T> __device__ static void go(T* p, T v) { unsafeAtomicAdd(p, v); }
};
template <> struct AtomAdd<false> {
  template <class T> __device__ static void go(T* p, T v) {
    unsigned* up = reinterpret_cast<unsigned*>(p);
    unsigned old = *up;
    while (true) {
      unsigned assumed = old;
      T cur = __builtin_bit_cast(T, assumed);
      T nw = __hadd2(cur, v);
      old = atomicCAS(up, assumed, __builtin_bit_cast(unsigned, nw));
      if (old == assumed) break;
    }
  }
};
__device__ __forceinline__ void atomAddH2(__half2* p, __half2 v) {
  AtomAdd<HasUnsafeAdd<__half2>::value>::go(p, v);
}

// ---------------------------------------------------------------------------
// Weight transpose fp32 -> f16 stash: out[slot][n*128+k] = W[k][n].
// Slots: 0 mf_w1, 1 g1_rel, 2 g1_root, 3 s1_w0, 4 s1_w1, 5 s1_w2,
//        6 g2_rel, 7 g2_root, 8 s2_w0[0:128], 9 s2_w0[128:256], 10 s2_w1
// ---------------------------------------------------------------------------
__global__ __launch_bounds__(256) void transpose_w(
    const float* p0, const float* p1, const float* p2, const float* p3,
    const float* p4, const float* p5, const float* p6, const float* p7,
    const float* p8, const float* p10, u16* dst)
{
  const float* src = p0; int eoff = 0;
  switch (blockIdx.y) {
    case 1: src = p1; break;  case 2: src = p2; break;
    case 3: src = p3; break;  case 4: src = p4; break;
    case 5: src = p5; break;  case 6: src = p6; break;
    case 7: src = p7; break;  case 8: src = p8; break;
    case 9: src = p8; eoff = 16384; break;
    case 10: src = p10; break;
    default: break;
  }
  u16* out = dst + (size_t)blockIdx.y * 16384;
  for (int i = threadIdx.x + blockIdx.x * 256; i < 16384; i += 2048) {
    int n = i >> 7, k = i & 127;
    out[i] = f2h_bits(src[eoff + k * 128 + n]);
  }
}

// ---------------------------------------------------------------------------
// CSR build: 2-stage counting sort (R11).
// ---------------------------------------------------------------------------
__global__ __launch_bounds__(256) void bucket_hist(const int* __restrict__ ei,
                                                   int* __restrict__ gbaseP) {
  __shared__ int cnt[512];
  int tid = threadIdx.x;
  for (int i = tid; i < 512; i += 256) cnt[i] = 0;
  __syncthreads();
  long e0 = (long)blockIdx.x * 8192;
  int n = (int)min((long)8192, (long)NEDGE - e0);
  for (int i = tid; i < n; i += 256) atomicAdd(&cnt[ei[NEDGE + e0 + i] >> 10], 1);
  __syncthreads();
  for (int b = tid; b < NBKT; b += 256)
    if (cnt[b]) atomicAdd(&gbaseP[b * BSTR], cnt[b]);
}

__global__ __launch_bounds__(512) void bucket_scan(int* gbaseP, int* gcurP) {
  __shared__ int sd[512];
  int tid = threadIdx.x;
  int v = (tid < NBKT) ? gbaseP[tid * BSTR] : 0;
  sd[tid] = v;
  __syncthreads();
  for (int off = 1; off < 512; off <<= 1) {
    int val = (tid >= off) ? sd[tid - off] : 0;
    __syncthreads();
    sd[tid] += val;
    __syncthreads();
  }
  int excl = sd[tid] - v;
  if (tid < NBKT) { gbaseP[tid * BSTR] = excl; gcurP[tid * BSTR] = excl; }
  if (tid == 0) gbaseP[NBKT * BSTR] = NEDGE;
}

__global__ __launch_bounds__(256) void partition_kernel(
    const int* __restrict__ ei, int* __restrict__ gcurP, int* __restrict__ adj)
{
  __shared__ int cnt[512], cnt2[512], rsv[512];
  int tid = threadIdx.x;
  for (int i = tid; i < 512; i += 256) { cnt[i] = 0; cnt2[i] = 0; }
  __syncthreads();
  long e0 = (long)blockIdx.x * 8192;
  int n = (int)min((long)8192, (long)NEDGE - e0);
  for (int i = tid; i < n; i += 256) atomicAdd(&cnt[ei[NEDGE + e0 + i] >> 10], 1);
  __syncthreads();
  for (int b = tid; b < NBKT; b += 256) {
    int c = cnt[b];
    rsv[b] = c ? atomicAdd(&gcurP[b * BSTR], c) : 0;
  }
  __syncthreads();
  for (int i = tid; i < n; i += 256) {
    int d = ei[NEDGE + e0 + i], s = ei[e0 + i];
    int b = d >> 10;
    int r = atomicAdd(&cnt2[b], 1);
    adj[rsv[b] + r] = ((d & 1023) << 19) | s;
  }
}

__global__ __launch_bounds__(256) void bucket_sort(
    const int* __restrict__ gbaseP, int* adj, int* __restrict__ cur,
    int* __restrict__ scratch)
{
  __shared__ __align__(16) int pk[8192];
  __shared__ __align__(16) int outb[8192];
  __shared__ int cnts[1024];
  __shared__ int base[1024];
  __shared__ int sd[256];
  int tid = threadIdx.x, b = blockIdx.x;
  int beg = gbaseP[b * BSTR], end = gbaseP[(b + 1) * BSTR];
  int cnt = end - beg;
  int n0 = b << 10;
  int nn = min(1024, NROWS - n0);
  bool fits = (cnt <= 8192);

  if (fits) {
    for (int i = tid; i < cnt; i += 256) pk[i] = adj[beg + i];
  } else {
    for (int i = tid; i < cnt; i += 256) scratch[beg + i] = adj[beg + i];
  }
  for (int i = tid; i < 1024; i += 256) cnts[i] = 0;
  __syncthreads();

  if (fits) {
    for (int i = tid; i < cnt; i += 256) atomicAdd(&cnts[pk[i] >> 19], 1);
  } else {
    for (int i = tid; i < cnt; i += 256) atomicAdd(&cnts[scratch[beg + i] >> 19], 1);
  }
  __syncthreads();

  int l0 = cnts[tid * 4], l1 = cnts[tid * 4 + 1],
      l2 = cnts[tid * 4 + 2], l3 = cnts[tid * 4 + 3];
  int p = l0 + l1 + l2 + l3;
  sd[tid] = p;
  __syncthreads();
  for (int off = 1; off < 256; off <<= 1) {
    int val = (tid >= off) ? sd[tid - off] : 0;
    __syncthreads();
    sd[tid] += val;
    __syncthreads();
  }
  int excl = sd[tid] - p;
  int lv[4] = {l0, l1, l2, l3};
#pragma unroll
  for (int k = 0; k < 4; ++k) {
    int node = tid * 4 + k;
    base[node] = excl;
    excl += lv[k];
    if (node < nn) cur[n0 + node] = beg + excl;
  }
  __syncthreads();
  for (int i = tid; i < 1024; i += 256) cnts[i] = 0;   // reuse as rank
  __syncthreads();

  if (fits) {
    for (int i = tid; i < cnt; i += 256) {
      int v = pk[i];
      int ld = v >> 19;
      int r = atomicAdd(&cnts[ld], 1);
      outb[base[ld] + r] = v & 0x7FFFF;
    }
    __syncthreads();
    for (int i = tid; i < cnt; i += 256) adj[beg + i] = outb[i];
  } else {
    for (int i = tid; i < cnt; i += 256) {
      int v = scratch[beg + i];
      int ld = v >> 19;
      int r = atomicAdd(&cnts[ld], 1);
      adj[beg + base[ld] + r] = v & 0x7FFFF;
    }
  }
}

// ---------------------------------------------------------------------------
// Gather segment-sum (R11 form + NT agg stores): wave per node, 8-row batch.
// x reads stay cached (6x reuse); agg output stream marked nontemporal so it
// doesn't evict x from L2/L3.
// ---------------------------------------------------------------------------
__global__ __launch_bounds__(256) void gather_agg(
    const u16* __restrict__ x, const int* __restrict__ cend,
    const int* __restrict__ adj, u16* __restrict__ agg)
{
  int wv = threadIdx.x >> 6, lane = threadIdx.x & 63;
  long node = (long)blockIdx.x * 4 + wv;
  if (node >= NROWS) return;
  int beg = (node == 0) ? 0 : cend[node - 1];
  int end = cend[node];
  float a0 = 0.f, a1 = 0.f;
  for (int j = beg; j < end; j += 8) {
    int take = end - j;
    if (take > 8) take = 8;
    int srcv = (lane < take) ? adj[j + lane] : 0;
    unsigned hb[8];
#pragma unroll
    for (int t = 0; t < 8; ++t) {
      if (t < take) {
        int src = __shfl(srcv, t);
        hb[t] = *reinterpret_cast<const unsigned*>(x + (long)src * 128 + lane * 2);
      }
    }
#pragma unroll
    for (int t = 0; t < 8; ++t) {
      if (t < take) {
        __half2 h = __builtin_bit_cast(__half2, hb[t]);
        a0 += (float)h.x;
        a1 += (float)h.y;
      }
    }
  }
  __half2 r;
  r.x = __float2half(a0);
  r.y = __float2half(a1);
  unsigned rv = __builtin_bit_cast(unsigned, r);
  __builtin_nontemporal_store(
      rv, reinterpret_cast<unsigned*>(agg + node * 128 + lane * 2));
}

// ---------------------------------------------------------------------------
// Atomic scatter (fallback path only).
// ---------------------------------------------------------------------------
__global__ __launch_bounds__(256) void scatter_kernel(
    const u16* __restrict__ x, const int* __restrict__ ei,
    __half2* __restrict__ agg)
{
  int gtid = blockIdx.x * 256 + threadIdx.x;
  int wid = gtid >> 6, lane = gtid & 63;
  int nw = gridDim.x * 4;
  for (int e = wid; e < NEDGE; e += nw) {
    int s = ei[e];
    int d = ei[NEDGE + e];
    __half2 h = *reinterpret_cast<const __half2*>(x + (long)s * 128 + lane * 2);
    atomAddH2(agg + (long)d * 64 + lane, h);
  }
}

// ---------------------------------------------------------------------------
// MFMA helpers. Layer inputs are single-read streams -> NT loads.
// ---------------------------------------------------------------------------
__device__ __forceinline__ void load_w_swz(const u16* Wt, short* ws, int tid) {
  for (int c = tid; c < 2048; c += 256) {
    int n = c >> 4, kb = c & 15;
    short8 v = *reinterpret_cast<const short8*>(Wt + n * 128 + kb * 8);
    *reinterpret_cast<short8*>(ws + ((n << 4) | (kb ^ (n & 15))) * 8) = v;
  }
}
__device__ __forceinline__ half8 read_b_swz(const short* ws, int col, int kb) {
  short8 v = *reinterpret_cast<const short8*>(ws + ((col << 4) | (kb ^ (col & 15))) * 8);
  return __builtin_bit_cast(half8, v);
}
__device__ __forceinline__ void gemm_global(f32x4* acc, const u16* X, long arow,
                                            bool active, const short* wbuf,
                                            int nl, int q) {
#pragma unroll
  for (int s = 0; s < 4; ++s) {
    int kofs = s * 32 + q * 8, kb = (s << 2) | q;
    half8 a = half8{0,0,0,0,0,0,0,0};
    if (active)
      a = __builtin_bit_cast(half8, ldnt8(X + arow * 128 + kofs));
#pragma unroll
    for (int c = 0; c < 8; ++c) {
      half8 b = read_b_swz(wbuf, (c << 4) | nl, kb);
      acc[c] = __builtin_amdgcn_mfma_f32_16x16x32_f16(a, b, acc[c], 0, 0, 0);
    }
  }
}
__device__ __forceinline__ void gemm_tile(f32x4* acc, const short* mytile,
                                          const short* wbuf, int nl, int q) {
#pragma unroll
  for (int s = 0; s < 4; ++s) {
    int kofs = s * 32 + q * 8, kb = (s << 2) | q;
    half8 a = __builtin_bit_cast(half8,
        *reinterpret_cast<const short8*>(&mytile[nl * 136 + kofs]));
#pragma unroll
    for (int c = 0; c < 8; ++c) {
      half8 b = read_b_swz(wbuf, (c << 4) | nl, kb);
      acc[c] = __builtin_amdgcn_mfma_f32_16x16x32_f16(a, b, acc[c], 0, 0, 0);
    }
  }
}
__device__ __forceinline__ void zero_acc(f32x4* acc) {
#pragma unroll
  for (int c = 0; c < 8; ++c) acc[c] = f32x4{0.f, 0.f, 0.f, 0.f};
}

// ---------------------------------------------------------------------------
// Persistent layer: weights staged ONCE, barrier-free chunk loop. In-place OK.
// ---------------------------------------------------------------------------
template<bool DUAL, bool ACT>
__global__ __launch_bounds__(256) void layer_kernel(
    const u16* X, const u16* X2,
    const u16* __restrict__ W1t, const u16* __restrict__ W2t,
    const float* __restrict__ bias, u16* Y)
{
  __shared__ __align__(16) short w1s[16384];
  __shared__ __align__(16) short w2s[DUAL ? 16384 : 8];
  __shared__ float bs[128];
  int tid = threadIdx.x;
  load_w_swz(W1t, w1s, tid);
  if constexpr (DUAL) load_w_swz(W2t, w2s, tid);
  if (tid < 128) bs[tid] = bias[tid];
  __syncthreads();

  int wv = tid >> 6, lane = tid & 63, nl = lane & 15, q = lane >> 4;
  for (int ch = blockIdx.x; ch < NCHUNK; ch += gridDim.x) {
    long r0 = (long)ch * 64 + wv * 16;
    if (r0 >= NROWS) continue;
    long arow = r0 + nl;
    f32x4 acc[8];
    zero_acc(acc);
    gemm_global(acc, X, arow, true, w1s, nl, q);
    if constexpr (DUAL) gemm_global(acc, X2, arow, true, w2s, nl, q);
#pragma unroll
    for (int c = 0; c < 8; ++c) {
      float bv = bs[(c << 4) | nl];
#pragma unroll
      for (int r = 0; r < 4; ++r) {
        float o = acc[c][r] + bv;
        if constexpr (ACT) o = eluf(o);
        Y[(r0 + q * 4 + r) * 128 + ((c << 4) | nl)] = f2h_bits(o);
      }
    }
  }
}

// ---------------------------------------------------------------------------
// Fused last layer: t = elu(X@s2w1 + b); out = t @ s2w2 + b2 (fp32).
// C-layout dot; shfl_xor reduce over the 16-lane nl group; nl==0 writes.
// ---------------------------------------------------------------------------
__global__ __launch_bounds__(256) void layer_final_kernel(
    const u16* __restrict__ X, const u16* __restrict__ W1t,
    const float* __restrict__ bias, const float* __restrict__ w2,
    const float* __restrict__ b2, float* __restrict__ out)
{
  __shared__ __align__(16) short w1s[16384];
  __shared__ float bs[128];
  __shared__ float w2s[256];
  __shared__ float b2s[2];
  int tid = threadIdx.x;
  load_w_swz(W1t, w1s, tid);
  if (tid < 128) bs[tid] = bias[tid];
  w2s[tid] = w2[tid];
  if (tid < 2) b2s[tid] = b2[tid];
  __syncthreads();

  int wv = tid >> 6, lane = tid & 63, nl = lane & 15, q = lane >> 4;
  for (int ch = blockIdx.x; ch < NCHUNK; ch += gridDim.x) {
    long r0 = (long)ch * 64 + wv * 16;
    if (r0 >= NROWS) continue;
    long arow = r0 + nl;
    f32x4 acc[8];
    zero_acc(acc);
    gemm_global(acc, X, arow, true, w1s, nl, q);
    float pr[4][2] = {{0.f,0.f},{0.f,0.f},{0.f,0.f},{0.f,0.f}};
#pragma unroll
    for (int c = 0; c < 8; ++c) {
      int col = (c << 4) | nl;
      float bv = bs[col];
      float w20 = w2s[col * 2], w21 = w2s[col * 2 + 1];
#pragma unroll
      for (int r = 0; r < 4; ++r) {
        float o = eluf(acc[c][r] + bv);
        pr[r][0] += o * w20;
        pr[r][1] += o * w21;
      }
    }
#pragma unroll
    for (int r = 0; r < 4; ++r)
#pragma unroll
      for (int m = 1; m < 16; m <<= 1) {
        pr[r][0] += __shfl_xor(pr[r][0], m);
        pr[r][1] += __shfl_xor(pr[r][1], m);
      }
    if (nl == 0) {
#pragma unroll
      for (int r = 0; r < 4; ++r) {
        out[(r0 + q * 4 + r) * 2]     = pr[r][0] + b2s[0];
        out[(r0 + q * 4 + r) * 2 + 1] = pr[r][1] + b2s[1];
      }
    }
  }
}

// ---------------------------------------------------------------------------
// Persistent mlp_face.
// ---------------------------------------------------------------------------
__global__ __launch_bounds__(256) void mlp_face_kernel(
    const float* __restrict__ hv, const float* __restrict__ w0,
    const float* __restrict__ b0, const u16* __restrict__ w1t,
    const float* __restrict__ b1, u16* ff)
{
  __shared__ __align__(16) short w1s[16384];
  __shared__ __align__(16) short act0[64 * 136];
  __shared__ float hvs[448];
  __shared__ float w0s[896];
  __shared__ float b0s[128];
  __shared__ float b1s[128];
  int tid = threadIdx.x;
  load_w_swz(w1t, w1s, tid);
  for (int i = tid; i < 896; i += 256) w0s[i] = w0[i];
  if (tid < 128) { b0s[tid] = b0[tid]; b1s[tid] = b1[tid]; }
  int wv = tid >> 6, lane = tid & 63, nl = lane & 15, q = lane >> 4;

  for (int ch = blockIdx.x; ch < NCHUNK; ch += gridDim.x) {
    long base = (long)ch * 64;
    __syncthreads();                       // protect hvs/act0 reuse
    for (int i = tid; i < 448; i += 256) {
      long g = base * 7 + i;
      hvs[i] = (g < (long)NROWS * 7) ? hv[g] : 0.0f;
    }
    __syncthreads();
    for (int idx = tid; idx < 8192; idx += 256) {
      int n = idx >> 7, c = idx & 127;
      float s = b0s[c];
#pragma unroll
      for (int k = 0; k < 7; ++k) s += hvs[n * 7 + k] * w0s[k * 128 + c];
      act0[n * 136 + c] = (short)f2h_bits(eluf(s));
    }
    __syncthreads();
    long r0 = base + wv * 16;
    if (r0 >= NROWS) continue;
    f32x4 acc[8];
    zero_acc(acc);
    gemm_tile(acc, &act0[(wv * 16) * 136], w1s, nl, q);
#pragma unroll
    for (int c = 0; c < 8; ++c) {
      float bv = b1s[(c << 4) | nl];
#pragma unroll
      for (int r = 0; r < 4; ++r)
        ff[(r0 + q * 4 + r) * 128 + ((c << 4) | nl)] = f2h_bits(eluf(acc[c][r] + bv));
    }
  }
}

// ---------------------------------------------------------------------------
// Standalone final (fallback path only).
// ---------------------------------------------------------------------------
__global__ __launch_bounds__(256) void final_kernel(
    const u16* __restrict__ x, const float* __restrict__ w2,
    const float* __restrict__ b2, float* __restrict__ out)
{
  __shared__ float w2s[256];
  __shared__ float b2s[2];
  int tid = threadIdx.x;
  w2s[tid] = w2[tid];
  if (tid < 2) b2s[tid] = b2[tid];
  __syncthreads();
  for (int ch = blockIdx.x; ch < NCHUNK; ch += gridDim.x) {
    long node = (long)ch * 64 + (tid >> 2);
    int q = tid & 3;
    if (node >= NROWS) continue;
    const u16* xr = x + node * 128 + q * 32;
    float p0 = 0.f, p1 = 0.f;
#pragma unroll
    for (int i = 0; i < 4; ++i) {
      short8 v = *reinterpret_cast<const short8*>(xr + i * 8);
#pragma unroll
      for (int j = 0; j < 8; ++j) {
        float f = h2f((u16)v[j]);
        int cidx = q * 32 + i * 8 + j;
        p0 += f * w2s[cidx * 2];
        p1 += f * w2s[cidx * 2 + 1];
      }
    }
    p0 += __shfl_xor(p0, 1); p0 += __shfl_xor(p0, 2);
    p1 += __shfl_xor(p1, 1); p1 += __shfl_xor(p1, 2);
    if (q == 0) {
      out[node * 2]     = p0 + b2s[0];
      out[node * 2 + 1] = p1 + b2s[1];
    }
  }
}

// ---------------------------------------------------------------------------
extern "C" void kernel_launch(void* const* d_in, const int* in_sizes, int n_in,
                              void* d_out, int out_size, void* d_ws, size_t ws_size,
                              hipStream_t stream) {
  const float* hv        = (const float*)d_in[0];
  const int*   ei        = (const int*)d_in[1];
  const float* mf_w0     = (const float*)d_in[2];
  const float* mf_b0     = (const float*)d_in[3];
  const float* mf_w1     = (const float*)d_in[4];
  const float* mf_b1     = (const float*)d_in[5];
  const float* g1_rel_w  = (const float*)d_in[6];
  const float* g1_rel_b  = (const float*)d_in[7];
  const float* g1_root_w = (const float*)d_in[8];
  const float* g2_rel_w  = (const float*)d_in[9];
  const float* g2_rel_b  = (const float*)d_in[10];
  const float* g2_root_w = (const float*)d_in[11];
  const float* s1_w0     = (const float*)d_in[12];
  const float* s1_b0     = (const float*)d_in[13];
  const float* s1_w1     = (const float*)d_in[14];
  const float* s1_b1     = (const float*)d_in[15];
  const float* s1_w2     = (const float*)d_in[16];
  const float* s1_b2     = (const float*)d_in[17];
  const float* s2_w0     = (const float*)d_in[18];
  const float* s2_b0     = (const float*)d_in[19];
  const float* s2_w1     = (const float*)d_in[20];
  const float* s2_b1     = (const float*)d_in[21];
  const float* s2_w2     = (const float*)d_in[22];
  const float* s2_b2     = (const float*)d_in[23];

  constexpr size_t ACT_BYTES = (size_t)NROWS * 128 * 2;     // 128e6
  constexpr size_t ADJ_BYTES = (size_t)NEDGE * 4;           // 12e6
  constexpr size_t WT_BYTES  = 11 * 16384 * 2;              // 360,448
  constexpr size_t CSR_NEED  = 2 * ACT_BYTES + ADJ_BYTES + WT_BYTES + 4096;

  char* ws = (char*)d_ws;
  u16* A   = (u16*)ws;
  u16* G   = (u16*)(ws + ACT_BYTES);
  int* adj = (int*)(ws + 2 * ACT_BYTES);
  const bool CSRP = ws_size >= CSR_NEED;                    // 268,364,544

  u16* wT;
  int* cur;     // per-node end offsets (2e6 B)
  int* gbaseP;  // padded bucket offsets
  int* gcurP;   // padded bucket cursors
  if (CSRP) {
    wT     = (u16*)(ws + 2 * ACT_BYTES + ADJ_BYTES);
    cur    = (int*)d_out;                                   // consumed pre-final
    gbaseP = (int*)((char*)d_out + 2000000);
    gcurP  = (int*)((char*)d_out + 2000000 + (NBKT + 1) * 64);
  } else {
    wT     = (u16*)d_out;   // fallback stash (final reads only d_in)
    cur    = nullptr; gbaseP = nullptr; gcurP = nullptr;
  }

  u16* mf_w1T   = wT + 0 * 16384;
  u16* g1_relT  = wT + 1 * 16384;
  u16* g1_rootT = wT + 2 * 16384;
  u16* s1_w0T   = wT + 3 * 16384;
  u16* s1_w1T   = wT + 4 * 16384;
  u16* s1_w2T   = wT + 5 * 16384;
  u16* g2_relT  = wT + 6 * 16384;
  u16* g2_rootT = wT + 7 * 16384;
  u16* s2w0loT  = wT + 8 * 16384;
  u16* s2w0hiT  = wT + 9 * 16384;
  u16* s2_w1T   = wT + 10 * 16384;

  transpose_w<<<dim3(8, 11), 256, 0, stream>>>(
      mf_w1, g1_rel_w, g1_root_w, s1_w0, s1_w1, s1_w2,
      g2_rel_w, g2_root_w, s2_w0, s2_w1, wT);

  const int gS = 1024;   // single-weight layer: ~33KB LDS -> 4 blocks/CU
  const int gD = 512;    // dual-weight layer:   ~65KB LDS -> 2 blocks/CU
  const int gM = 512;    // mlp_face:            ~56KB LDS -> 2 blocks/CU
  const int gF = 1024;   // fallback final
  const int gT = (NEDGE + 8191) / 8192;     // 367 edge tiles
  const int gn = (NROWS + 3) / 4;           // 125000 (gather: 4 nodes/block)

  if (CSRP) {
    // ---- CSR via 2-stage counting sort ----
    (void)hipMemsetAsync(gbaseP, 0, (size_t)(2 * NBKT + 1) * 64, stream);
    bucket_hist<<<gT, 256, 0, stream>>>(ei, gbaseP);
    bucket_scan<<<1, 512, 0, stream>>>(gbaseP, gcurP);
    partition_kernel<<<gT, 256, 0, stream>>>(ei, gcurP, adj);
    bucket_sort<<<NBKT, 256, 0, stream>>>(gbaseP, adj, cur, (int*)G);

    mlp_face_kernel<<<gM, 256, 0, stream>>>(hv, mf_w0, mf_b0, mf_w1T, mf_b1, A); // A=ff
    gather_agg<<<gn, 256, 0, stream>>>(A, cur, adj, G);                           // G=agg1
    layer_kernel<true,  true ><<<gD, 256, 0, stream>>>(G, A, g1_relT, g1_rootT, g1_rel_b, A); // A=h
    layer_kernel<false, true ><<<gS, 256, 0, stream>>>(A, nullptr, s1_w0T, nullptr, s1_b0, A);
    layer_kernel<false, true ><<<gS, 256, 0, stream>>>(A, nullptr, s1_w1T, nullptr, s1_b1, A);
    layer_kernel<false, true ><<<gS, 256, 0, stream>>>(A, nullptr, s1_w2T, nullptr, s1_b2, A);
    gather_agg<<<gn, 256, 0, stream>>>(A, cur, adj, G);                           // G=agg2
    layer_kernel<true,  false><<<gD, 256, 0, stream>>>(G, A, g2_relT, g2_rootT, g2_rel_b, A); // A=h2
    mlp_face_kernel<<<gM, 256, 0, stream>>>(hv, mf_w0, mf_b0, mf_w1T, mf_b1, G);  // G=ff
    layer_kernel<true,  true ><<<gD, 256, 0, stream>>>(G, A, s2w0loT, s2w0hiT, s2_b0, G);
    layer_final_kernel<<<gS, 256, 0, stream>>>(G, s2_w1T, s2_b1, s2_w2, s2_b2,
                                               (float*)d_out);
  } else {
    mlp_face_kernel<<<gM, 256, 0, stream>>>(hv, mf_w0, mf_b0, mf_w1T, mf_b1, A);
    (void)hipMemsetAsync(G, 0, ACT_BYTES, stream);
    scatter_kernel<<<4096, 256, 0, stream>>>(A, ei, (__half2*)G);
    layer_kernel<true,  true ><<<gD, 256, 0, stream>>>(G, A, g1_relT, g1_rootT, g1_rel_b, A);
    layer_kernel<false, true ><<<gS, 256, 0, stream>>>(A, nullptr, s1_w0T, nullptr, s1_b0, A);
    layer_kernel<false, true ><<<gS, 256, 0, stream>>>(A, nullptr, s1_w1T, nullptr, s1_b1, A);
    layer_kernel<false, true ><<<gS, 256, 0, stream>>>(A, nullptr, s1_w2T, nullptr, s1_b2, A);
    (void)hipMemsetAsync(G, 0, ACT_BYTES, stream);
    scatter_kernel<<<4096, 256, 0, stream>>>(A, ei, (__half2*)G);
    layer_kernel<true,  false><<<gD, 256, 0, stream>>>(G, A, g2_relT, g2_rootT, g2_rel_b, A);
    mlp_face_kernel<<<gM, 256, 0, stream>>>(hv, mf_w0, mf_b0, mf_w1T, mf_b1, G);
    layer_kernel<true,  true ><<<gD, 256, 0, stream>>>(G, A, s2w0loT, s2w0hiT, s2_b0, G);
    layer_final_kernel<<<gS, 256, 0, stream>>>(G, s2_w1T, s2_b1, s2_w2, s2_b2,
                                               (float*)d_out);
  }
}

// Round 15
// 1350.066 us; speedup vs baseline: 1.1193x; 1.1193x over previous
//
#include <hip/hip_runtime.h>
#include <hip/hip_bf16.h>
#include <hip/hip_fp16.h>
#include <type_traits>
#include <utility>

// FaceModel: N=500000 nodes, E=3000000 edges, F=128. fp32 in/out, f16 internal.
// R15: revert R14's NT hints (regressed 1439->1511; FETCH unchanged -> gfx950
// NT bits don't steer L3 victim selection). Gather reworked: 32 lanes x 8B
// per row (2 rows per load instr, halves split even/odd edges; one shfl
// serves both halves; shfl_xor(32) combine). Keeps 1 node/wave + 500k waves
// (R12 lesson) while halving issue slots and doubling rows in flight.
// Everything else identical to R13 (1439us).

#define NROWS 500000
#define NEDGE 3000000
#define NCHUNK ((NROWS + 63) / 64)          // 7813
#define NBKT 489                             // ceil(NROWS/1024)
#define BSTR 16                              // padded int stride (64B)

typedef unsigned short u16;
using short8 = __attribute__((ext_vector_type(8))) short;
using half8  = __attribute__((ext_vector_type(8))) _Float16;
using f32x4  = __attribute__((ext_vector_type(4))) float;

__device__ __forceinline__ u16 f2h_bits(float f) {
  _Float16 h = (_Float16)f;
  return __builtin_bit_cast(u16, h);
}
__device__ __forceinline__ float h2f(u16 b) {
  return (float)__builtin_bit_cast(_Float16, b);
}
__device__ __forceinline__ float eluf(float x) { return x > 0.0f ? x : expm1f(x); }

// --- f16 packed atomic add with fallback (scatter fallback path only) ------
template <typename T, typename = void> struct HasUnsafeAdd : std::false_type {};
template <typename T>
struct HasUnsafeAdd<T, std::void_t<decltype(unsafeAtomicAdd(
    std::declval<T*>(), std::declval<T>()))>> : std::true_type {};
template <bool HAS> struct AtomAdd;
template <> struct AtomAdd<true> {
  template <class T> __device__ static void go(T* p, T v) { unsafeAtomicAdd(p, v); }
};
template <> struct AtomAdd<false> {
  template <class T> __device__ static void go(T* p, T v) {
    unsigned* up = reinterpret_cast<unsigned*>(p);
    unsigned old = *up;
    while (true) {
      unsigned assumed = old;
      T cur = __builtin_bit_cast(T, assumed);
      T nw = __hadd2(cur, v);
      old = atomicCAS(up, assumed, __builtin_bit_cast(unsigned, nw));
      if (old == assumed) break;
    }
  }
};
__device__ __forceinline__ void atomAddH2(__half2* p, __half2 v) {
  AtomAdd<HasUnsafeAdd<__half2>::value>::go(p, v);
}

// ---------------------------------------------------------------------------
// Weight transpose fp32 -> f16 stash: out[slot][n*128+k] = W[k][n].
// Slots: 0 mf_w1, 1 g1_rel, 2 g1_root, 3 s1_w0, 4 s1_w1, 5 s1_w2,
//        6 g2_rel, 7 g2_root, 8 s2_w0[0:128], 9 s2_w0[128:256], 10 s2_w1
// ---------------------------------------------------------------------------
__global__ __launch_bounds__(256) void transpose_w(
    const float* p0, const float* p1, const float* p2, const float* p3,
    const float* p4, const float* p5, const float* p6, const float* p7,
    const float* p8, const float* p10, u16* dst)
{
  const float* src = p0; int eoff = 0;
  switch (blockIdx.y) {
    case 1: src = p1; break;  case 2: src = p2; break;
    case 3: src = p3; break;  case 4: src = p4; break;
    case 5: src = p5; break;  case 6: src = p6; break;
    case 7: src = p7; break;  case 8: src = p8; break;
    case 9: src = p8; eoff = 16384; break;
    case 10: src = p10; break;
    default: break;
  }
  u16* out = dst + (size_t)blockIdx.y * 16384;
  for (int i = threadIdx.x + blockIdx.x * 256; i < 16384; i += 2048) {
    int n = i >> 7, k = i & 127;
    out[i] = f2h_bits(src[eoff + k * 128 + n]);
  }
}

// ---------------------------------------------------------------------------
// CSR build: 2-stage counting sort (R11).
// ---------------------------------------------------------------------------
__global__ __launch_bounds__(256) void bucket_hist(const int* __restrict__ ei,
                                                   int* __restrict__ gbaseP) {
  __shared__ int cnt[512];
  int tid = threadIdx.x;
  for (int i = tid; i < 512; i += 256) cnt[i] = 0;
  __syncthreads();
  long e0 = (long)blockIdx.x * 8192;
  int n = (int)min((long)8192, (long)NEDGE - e0);
  for (int i = tid; i < n; i += 256) atomicAdd(&cnt[ei[NEDGE + e0 + i] >> 10], 1);
  __syncthreads();
  for (int b = tid; b < NBKT; b += 256)
    if (cnt[b]) atomicAdd(&gbaseP[b * BSTR], cnt[b]);
}

__global__ __launch_bounds__(512) void bucket_scan(int* gbaseP, int* gcurP) {
  __shared__ int sd[512];
  int tid = threadIdx.x;
  int v = (tid < NBKT) ? gbaseP[tid * BSTR] : 0;
  sd[tid] = v;
  __syncthreads();
  for (int off = 1; off < 512; off <<= 1) {
    int val = (tid >= off) ? sd[tid - off] : 0;
    __syncthreads();
    sd[tid] += val;
    __syncthreads();
  }
  int excl = sd[tid] - v;
  if (tid < NBKT) { gbaseP[tid * BSTR] = excl; gcurP[tid * BSTR] = excl; }
  if (tid == 0) gbaseP[NBKT * BSTR] = NEDGE;
}

__global__ __launch_bounds__(256) void partition_kernel(
    const int* __restrict__ ei, int* __restrict__ gcurP, int* __restrict__ adj)
{
  __shared__ int cnt[512], cnt2[512], rsv[512];
  int tid = threadIdx.x;
  for (int i = tid; i < 512; i += 256) { cnt[i] = 0; cnt2[i] = 0; }
  __syncthreads();
  long e0 = (long)blockIdx.x * 8192;
  int n = (int)min((long)8192, (long)NEDGE - e0);
  for (int i = tid; i < n; i += 256) atomicAdd(&cnt[ei[NEDGE + e0 + i] >> 10], 1);
  __syncthreads();
  for (int b = tid; b < NBKT; b += 256) {
    int c = cnt[b];
    rsv[b] = c ? atomicAdd(&gcurP[b * BSTR], c) : 0;
  }
  __syncthreads();
  for (int i = tid; i < n; i += 256) {
    int d = ei[NEDGE + e0 + i], s = ei[e0 + i];
    int b = d >> 10;
    int r = atomicAdd(&cnt2[b], 1);
    adj[rsv[b] + r] = ((d & 1023) << 19) | s;
  }
}

__global__ __launch_bounds__(256) void bucket_sort(
    const int* __restrict__ gbaseP, int* adj, int* __restrict__ cur,
    int* __restrict__ scratch)
{
  __shared__ __align__(16) int pk[8192];
  __shared__ __align__(16) int outb[8192];
  __shared__ int cnts[1024];
  __shared__ int base[1024];
  __shared__ int sd[256];
  int tid = threadIdx.x, b = blockIdx.x;
  int beg = gbaseP[b * BSTR], end = gbaseP[(b + 1) * BSTR];
  int cnt = end - beg;
  int n0 = b << 10;
  int nn = min(1024, NROWS - n0);
  bool fits = (cnt <= 8192);

  if (fits) {
    for (int i = tid; i < cnt; i += 256) pk[i] = adj[beg + i];
  } else {
    for (int i = tid; i < cnt; i += 256) scratch[beg + i] = adj[beg + i];
  }
  for (int i = tid; i < 1024; i += 256) cnts[i] = 0;
  __syncthreads();

  if (fits) {
    for (int i = tid; i < cnt; i += 256) atomicAdd(&cnts[pk[i] >> 19], 1);
  } else {
    for (int i = tid; i < cnt; i += 256) atomicAdd(&cnts[scratch[beg + i] >> 19], 1);
  }
  __syncthreads();

  int l0 = cnts[tid * 4], l1 = cnts[tid * 4 + 1],
      l2 = cnts[tid * 4 + 2], l3 = cnts[tid * 4 + 3];
  int p = l0 + l1 + l2 + l3;
  sd[tid] = p;
  __syncthreads();
  for (int off = 1; off < 256; off <<= 1) {
    int val = (tid >= off) ? sd[tid - off] : 0;
    __syncthreads();
    sd[tid] += val;
    __syncthreads();
  }
  int excl = sd[tid] - p;
  int lv[4] = {l0, l1, l2, l3};
#pragma unroll
  for (int k = 0; k < 4; ++k) {
    int node = tid * 4 + k;
    base[node] = excl;
    excl += lv[k];
    if (node < nn) cur[n0 + node] = beg + excl;
  }
  __syncthreads();
  for (int i = tid; i < 1024; i += 256) cnts[i] = 0;   // reuse as rank
  __syncthreads();

  if (fits) {
    for (int i = tid; i < cnt; i += 256) {
      int v = pk[i];
      int ld = v >> 19;
      int r = atomicAdd(&cnts[ld], 1);
      outb[base[ld] + r] = v & 0x7FFFF;
    }
    __syncthreads();
    for (int i = tid; i < cnt; i += 256) adj[beg + i] = outb[i];
  } else {
    for (int i = tid; i < cnt; i += 256) {
      int v = scratch[beg + i];
      int ld = v >> 19;
      int r = atomicAdd(&cnts[ld], 1);
      adj[beg + base[ld] + r] = v & 0x7FFFF;
    }
  }
}

// ---------------------------------------------------------------------------
// Gather segment-sum: wave per node; 32 lanes x 8B per row, wave halves take
// even/odd edges. Per 16 edges: 8 uint2 loads + 8 shfls (vs 16+16 in R13).
// shfl_xor(32) folds halves; lanes 0-31 write 8B each (coalesced 256B row).
// ---------------------------------------------------------------------------
__global__ __launch_bounds__(256) void gather_agg(
    const u16* __restrict__ x, const int* __restrict__ cend,
    const int* __restrict__ adj, u16* __restrict__ agg)
{
  int wv = threadIdx.x >> 6, lane = threadIdx.x & 63;
  long node = (long)blockIdx.x * 4 + wv;
  if (node >= NROWS) return;
  int beg = (node == 0) ? 0 : cend[node - 1];
  int end = cend[node];
  int half = lane >> 5;          // 0: even edges, 1: odd edges
  int cl = lane & 31;            // column group: cols [4cl, 4cl+4)
  float a0 = 0.f, a1 = 0.f, a2 = 0.f, a3 = 0.f;
  for (int j = beg; j < end; j += 16) {
    int take = end - j;
    if (take > 16) take = 16;
    int srcv = (lane < take) ? adj[j + lane] : 0;
    uint2 hb[8];
#pragma unroll
    for (int t = 0; t < 8; ++t) {
      int e = 2 * t + half;
      if (e < take) {
        int src = __shfl(srcv, e);
        hb[t] = *reinterpret_cast<const uint2*>(x + (long)src * 128 + cl * 4);
      }
    }
#pragma unroll
    for (int t = 0; t < 8; ++t) {
      int e = 2 * t + half;
      if (e < take) {
        __half2 h0 = __builtin_bit_cast(__half2, hb[t].x);
        __half2 h1 = __builtin_bit_cast(__half2, hb[t].y);
        a0 += (float)h0.x;
        a1 += (float)h0.y;
        a2 += (float)h1.x;
        a3 += (float)h1.y;
      }
    }
  }
  a0 += __shfl_xor(a0, 32);
  a1 += __shfl_xor(a1, 32);
  a2 += __shfl_xor(a2, 32);
  a3 += __shfl_xor(a3, 32);
  if (half == 0) {
    __half2 r0, r1;
    r0.x = __float2half(a0); r0.y = __float2half(a1);
    r1.x = __float2half(a2); r1.y = __float2half(a3);
    uint2 rv;
    rv.x = __builtin_bit_cast(unsigned, r0);
    rv.y = __builtin_bit_cast(unsigned, r1);
    *reinterpret_cast<uint2*>(agg + node * 128 + cl * 4) = rv;
  }
}

// ---------------------------------------------------------------------------
// Atomic scatter (fallback path only).
// ---------------------------------------------------------------------------
__global__ __launch_bounds__(256) void scatter_kernel(
    const u16* __restrict__ x, const int* __restrict__ ei,
    __half2* __restrict__ agg)
{
  int gtid = blockIdx.x * 256 + threadIdx.x;
  int wid = gtid >> 6, lane = gtid & 63;
  int nw = gridDim.x * 4;
  for (int e = wid; e < NEDGE; e += nw) {
    int s = ei[e];
    int d = ei[NEDGE + e];
    __half2 h = *reinterpret_cast<const __half2*>(x + (long)s * 128 + lane * 2);
    atomAddH2(agg + (long)d * 64 + lane, h);
  }
}

// ---------------------------------------------------------------------------
// MFMA helpers.
// ---------------------------------------------------------------------------
__device__ __forceinline__ void load_w_swz(const u16* Wt, short* ws, int tid) {
  for (int c = tid; c < 2048; c += 256) {
    int n = c >> 4, kb = c & 15;
    short8 v = *reinterpret_cast<const short8*>(Wt + n * 128 + kb * 8);
    *reinterpret_cast<short8*>(ws + ((n << 4) | (kb ^ (n & 15))) * 8) = v;
  }
}
__device__ __forceinline__ half8 read_b_swz(const short* ws, int col, int kb) {
  short8 v = *reinterpret_cast<const short8*>(ws + ((col << 4) | (kb ^ (col & 15))) * 8);
  return __builtin_bit_cast(half8, v);
}
__device__ __forceinline__ void gemm_global(f32x4* acc, const u16* X, long arow,
                                            bool active, const short* wbuf,
                                            int nl, int q) {
#pragma unroll
  for (int s = 0; s < 4; ++s) {
    int kofs = s * 32 + q * 8, kb = (s << 2) | q;
    half8 a = half8{0,0,0,0,0,0,0,0};
    if (active)
      a = __builtin_bit_cast(half8,
          *reinterpret_cast<const short8*>(X + arow * 128 + kofs));
#pragma unroll
    for (int c = 0; c < 8; ++c) {
      half8 b = read_b_swz(wbuf, (c << 4) | nl, kb);
      acc[c] = __builtin_amdgcn_mfma_f32_16x16x32_f16(a, b, acc[c], 0, 0, 0);
    }
  }
}
__device__ __forceinline__ void gemm_tile(f32x4* acc, const short* mytile,
                                          const short* wbuf, int nl, int q) {
#pragma unroll
  for (int s = 0; s < 4; ++s) {
    int kofs = s * 32 + q * 8, kb = (s << 2) | q;
    half8 a = __builtin_bit_cast(half8,
        *reinterpret_cast<const short8*>(&mytile[nl * 136 + kofs]));
#pragma unroll
    for (int c = 0; c < 8; ++c) {
      half8 b = read_b_swz(wbuf, (c << 4) | nl, kb);
      acc[c] = __builtin_amdgcn_mfma_f32_16x16x32_f16(a, b, acc[c], 0, 0, 0);
    }
  }
}
__device__ __forceinline__ void zero_acc(f32x4* acc) {
#pragma unroll
  for (int c = 0; c < 8; ++c) acc[c] = f32x4{0.f, 0.f, 0.f, 0.f};
}

// ---------------------------------------------------------------------------
// Persistent layer: weights staged ONCE, barrier-free chunk loop. In-place OK.
// ---------------------------------------------------------------------------
template<bool DUAL, bool ACT>
__global__ __launch_bounds__(256) void layer_kernel(
    const u16* X, const u16* X2,
    const u16* __restrict__ W1t, const u16* __restrict__ W2t,
    const float* __restrict__ bias, u16* Y)
{
  __shared__ __align__(16) short w1s[16384];
  __shared__ __align__(16) short w2s[DUAL ? 16384 : 8];
  __shared__ float bs[128];
  int tid = threadIdx.x;
  load_w_swz(W1t, w1s, tid);
  if constexpr (DUAL) load_w_swz(W2t, w2s, tid);
  if (tid < 128) bs[tid] = bias[tid];
  __syncthreads();

  int wv = tid >> 6, lane = tid & 63, nl = lane & 15, q = lane >> 4;
  for (int ch = blockIdx.x; ch < NCHUNK; ch += gridDim.x) {
    long r0 = (long)ch * 64 + wv * 16;
    if (r0 >= NROWS) continue;
    long arow = r0 + nl;
    f32x4 acc[8];
    zero_acc(acc);
    gemm_global(acc, X, arow, true, w1s, nl, q);
    if constexpr (DUAL) gemm_global(acc, X2, arow, true, w2s, nl, q);
#pragma unroll
    for (int c = 0; c < 8; ++c) {
      float bv = bs[(c << 4) | nl];
#pragma unroll
      for (int r = 0; r < 4; ++r) {
        float o = acc[c][r] + bv;
        if constexpr (ACT) o = eluf(o);
        Y[(r0 + q * 4 + r) * 128 + ((c << 4) | nl)] = f2h_bits(o);
      }
    }
  }
}

// ---------------------------------------------------------------------------
// Fused last layer: t = elu(X@s2w1 + b); out = t @ s2w2 + b2 (fp32).
// C-layout dot; shfl_xor reduce over the 16-lane nl group; nl==0 writes.
// ---------------------------------------------------------------------------
__global__ __launch_bounds__(256) void layer_final_kernel(
    const u16* __restrict__ X, const u16* __restrict__ W1t,
    const float* __restrict__ bias, const float* __restrict__ w2,
    const float* __restrict__ b2, float* __restrict__ out)
{
  __shared__ __align__(16) short w1s[16384];
  __shared__ float bs[128];
  __shared__ float w2s[256];
  __shared__ float b2s[2];
  int tid = threadIdx.x;
  load_w_swz(W1t, w1s, tid);
  if (tid < 128) bs[tid] = bias[tid];
  w2s[tid] = w2[tid];
  if (tid < 2) b2s[tid] = b2[tid];
  __syncthreads();

  int wv = tid >> 6, lane = tid & 63, nl = lane & 15, q = lane >> 4;
  for (int ch = blockIdx.x; ch < NCHUNK; ch += gridDim.x) {
    long r0 = (long)ch * 64 + wv * 16;
    if (r0 >= NROWS) continue;
    long arow = r0 + nl;
    f32x4 acc[8];
    zero_acc(acc);
    gemm_global(acc, X, arow, true, w1s, nl, q);
    float pr[4][2] = {{0.f,0.f},{0.f,0.f},{0.f,0.f},{0.f,0.f}};
#pragma unroll
    for (int c = 0; c < 8; ++c) {
      int col = (c << 4) | nl;
      float bv = bs[col];
      float w20 = w2s[col * 2], w21 = w2s[col * 2 + 1];
#pragma unroll
      for (int r = 0; r < 4; ++r) {
        float o = eluf(acc[c][r] + bv);
        pr[r][0] += o * w20;
        pr[r][1] += o * w21;
      }
    }
#pragma unroll
    for (int r = 0; r < 4; ++r)
#pragma unroll
      for (int m = 1; m < 16; m <<= 1) {
        pr[r][0] += __shfl_xor(pr[r][0], m);
        pr[r][1] += __shfl_xor(pr[r][1], m);
      }
    if (nl == 0) {
#pragma unroll
      for (int r = 0; r < 4; ++r) {
        out[(r0 + q * 4 + r) * 2]     = pr[r][0] + b2s[0];
        out[(r0 + q * 4 + r) * 2 + 1] = pr[r][1] + b2s[1];
      }
    }
  }
}

// ---------------------------------------------------------------------------
// Persistent mlp_face.
// ---------------------------------------------------------------------------
__global__ __launch_bounds__(256) void mlp_face_kernel(
    const float* __restrict__ hv, const float* __restrict__ w0,
    const float* __restrict__ b0, const u16* __restrict__ w1t,
    const float* __restrict__ b1, u16* ff)
{
  __shared__ __align__(16) short w1s[16384];
  __shared__ __align__(16) short act0[64 * 136];
  __shared__ float hvs[448];
  __shared__ float w0s[896];
  __shared__ float b0s[128];
  __shared__ float b1s[128];
  int tid = threadIdx.x;
  load_w_swz(w1t, w1s, tid);
  for (int i = tid; i < 896; i += 256) w0s[i] = w0[i];
  if (tid < 128) { b0s[tid] = b0[tid]; b1s[tid] = b1[tid]; }
  int wv = tid >> 6, lane = tid & 63, nl = lane & 15, q = lane >> 4;

  for (int ch = blockIdx.x; ch < NCHUNK; ch += gridDim.x) {
    long base = (long)ch * 64;
    __syncthreads();                       // protect hvs/act0 reuse
    for (int i = tid; i < 448; i += 256) {
      long g = base * 7 + i;
      hvs[i] = (g < (long)NROWS * 7) ? hv[g] : 0.0f;
    }
    __syncthreads();
    for (int idx = tid; idx < 8192; idx += 256) {
      int n = idx >> 7, c = idx & 127;
      float s = b0s[c];
#pragma unroll
      for (int k = 0; k < 7; ++k) s += hvs[n * 7 + k] * w0s[k * 128 + c];
      act0[n * 136 + c] = (short)f2h_bits(eluf(s));
    }
    __syncthreads();
    long r0 = base + wv * 16;
    if (r0 >= NROWS) continue;
    f32x4 acc[8];
    zero_acc(acc);
    gemm_tile(acc, &act0[(wv * 16) * 136], w1s, nl, q);
#pragma unroll
    for (int c = 0; c < 8; ++c) {
      float bv = b1s[(c << 4) | nl];
#pragma unroll
      for (int r = 0; r < 4; ++r)
        ff[(r0 + q * 4 + r) * 128 + ((c << 4) | nl)] = f2h_bits(eluf(acc[c][r] + bv));
    }
  }
}

// ---------------------------------------------------------------------------
// Standalone final (fallback path only).
// ---------------------------------------------------------------------------
__global__ __launch_bounds__(256) void final_kernel(
    const u16* __restrict__ x, const float* __restrict__ w2,
    const float* __restrict__ b2, float* __restrict__ out)
{
  __shared__ float w2s[256];
  __shared__ float b2s[2];
  int tid = threadIdx.x;
  w2s[tid] = w2[tid];
  if (tid < 2) b2s[tid] = b2[tid];
  __syncthreads();
  for (int ch = blockIdx.x; ch < NCHUNK; ch += gridDim.x) {
    long node = (long)ch * 64 + (tid >> 2);
    int q = tid & 3;
    if (node >= NROWS) continue;
    const u16* xr = x + node * 128 + q * 32;
    float p0 = 0.f, p1 = 0.f;
#pragma unroll
    for (int i = 0; i < 4; ++i) {
      short8 v = *reinterpret_cast<const short8*>(xr + i * 8);
#pragma unroll
      for (int j = 0; j < 8; ++j) {
        float f = h2f((u16)v[j]);
        int cidx = q * 32 + i * 8 + j;
        p0 += f * w2s[cidx * 2];
        p1 += f * w2s[cidx * 2 + 1];
      }
    }
    p0 += __shfl_xor(p0, 1); p0 += __shfl_xor(p0, 2);
    p1 += __shfl_xor(p1, 1); p1 += __shfl_xor(p1, 2);
    if (q == 0) {
      out[node * 2]     = p0 + b2s[0];
      out[node * 2 + 1] = p1 + b2s[1];
    }
  }
}

// ---------------------------------------------------------------------------
extern "C" void kernel_launch(void* const* d_in, const int* in_sizes, int n_in,
                              void* d_out, int out_size, void* d_ws, size_t ws_size,
                              hipStream_t stream) {
  const float* hv        = (const float*)d_in[0];
  const int*   ei        = (const int*)d_in[1];
  const float* mf_w0     = (const float*)d_in[2];
  const float* mf_b0     = (const float*)d_in[3];
  const float* mf_w1     = (const float*)d_in[4];
  const float* mf_b1     = (const float*)d_in[5];
  const float* g1_rel_w  = (const float*)d_in[6];
  const float* g1_rel_b  = (const float*)d_in[7];
  const float* g1_root_w = (const float*)d_in[8];
  const float* g2_rel_w  = (const float*)d_in[9];
  const float* g2_rel_b  = (const float*)d_in[10];
  const float* g2_root_w = (const float*)d_in[11];
  const float* s1_w0     = (const float*)d_in[12];
  const float* s1_b0     = (const float*)d_in[13];
  const float* s1_w1     = (const float*)d_in[14];
  const float* s1_b1     = (const float*)d_in[15];
  const float* s1_w2     = (const float*)d_in[16];
  const float* s1_b2     = (const float*)d_in[17];
  const float* s2_w0     = (const float*)d_in[18];
  const float* s2_b0     = (const float*)d_in[19];
  const float* s2_w1     = (const float*)d_in[20];
  const float* s2_b1     = (const float*)d_in[21];
  const float* s2_w2     = (const float*)d_in[22];
  const float* s2_b2     = (const float*)d_in[23];

  constexpr size_t ACT_BYTES = (size_t)NROWS * 128 * 2;     // 128e6
  constexpr size_t ADJ_BYTES = (size_t)NEDGE * 4;           // 12e6
  constexpr size_t WT_BYTES  = 11 * 16384 * 2;              // 360,448
  constexpr size_t CSR_NEED  = 2 * ACT_BYTES + ADJ_BYTES + WT_BYTES + 4096;

  char* ws = (char*)d_ws;
  u16* A   = (u16*)ws;
  u16* G   = (u16*)(ws + ACT_BYTES);
  int* adj = (int*)(ws + 2 * ACT_BYTES);
  const bool CSRP = ws_size >= CSR_NEED;                    // 268,364,544

  u16* wT;
  int* cur;     // per-node end offsets (2e6 B)
  int* gbaseP;  // padded bucket offsets
  int* gcurP;   // padded bucket cursors
  if (CSRP) {
    wT     = (u16*)(ws + 2 * ACT_BYTES + ADJ_BYTES);
    cur    = (int*)d_out;                                   // consumed pre-final
    gbaseP = (int*)((char*)d_out + 2000000);
    gcurP  = (int*)((char*)d_out + 2000000 + (NBKT + 1) * 64);
  } else {
    wT     = (u16*)d_out;   // fallback stash (final reads only d_in)
    cur    = nullptr; gbaseP = nullptr; gcurP = nullptr;
  }

  u16* mf_w1T   = wT + 0 * 16384;
  u16* g1_relT  = wT + 1 * 16384;
  u16* g1_rootT = wT + 2 * 16384;
  u16* s1_w0T   = wT + 3 * 16384;
  u16* s1_w1T   = wT + 4 * 16384;
  u16* s1_w2T   = wT + 5 * 16384;
  u16* g2_relT  = wT + 6 * 16384;
  u16* g2_rootT = wT + 7 * 16384;
  u16* s2w0loT  = wT + 8 * 16384;
  u16* s2w0hiT  = wT + 9 * 16384;
  u16* s2_w1T   = wT + 10 * 16384;

  transpose_w<<<dim3(8, 11), 256, 0, stream>>>(
      mf_w1, g1_rel_w, g1_root_w, s1_w0, s1_w1, s1_w2,
      g2_rel_w, g2_root_w, s2_w0, s2_w1, wT);

  const int gS = 1024;   // single-weight layer: ~33KB LDS -> 4 blocks/CU
  const int gD = 512;    // dual-weight layer:   ~65KB LDS -> 2 blocks/CU
  const int gM = 512;    // mlp_face:            ~56KB LDS -> 2 blocks/CU
  const int gT = (NEDGE + 8191) / 8192;     // 367 edge tiles
  const int gn = (NROWS + 3) / 4;           // 125000 (gather: 4 nodes/block)

  if (CSRP) {
    // ---- CSR via 2-stage counting sort ----
    (void)hipMemsetAsync(gbaseP, 0, (size_t)(2 * NBKT + 1) * 64, stream);
    bucket_hist<<<gT, 256, 0, stream>>>(ei, gbaseP);
    bucket_scan<<<1, 512, 0, stream>>>(gbaseP, gcurP);
    partition_kernel<<<gT, 256, 0, stream>>>(ei, gcurP, adj);
    bucket_sort<<<NBKT, 256, 0, stream>>>(gbaseP, adj, cur, (int*)G);

    mlp_face_kernel<<<gM, 256, 0, stream>>>(hv, mf_w0, mf_b0, mf_w1T, mf_b1, A); // A=ff
    gather_agg<<<gn, 256, 0, stream>>>(A, cur, adj, G);                           // G=agg1
    layer_kernel<true,  true ><<<gD, 256, 0, stream>>>(G, A, g1_relT, g1_rootT, g1_rel_b, A); // A=h
    layer_kernel<false, true ><<<gS, 256, 0, stream>>>(A, nullptr, s1_w0T, nullptr, s1_b0, A);
    layer_kernel<false, true ><<<gS, 256, 0, stream>>>(A, nullptr, s1_w1T, nullptr, s1_b1, A);
    layer_kernel<false, true ><<<gS, 256, 0, stream>>>(A, nullptr, s1_w2T, nullptr, s1_b2, A);
    gather_agg<<<gn, 256, 0, stream>>>(A, cur, adj, G);                           // G=agg2
    layer_kernel<true,  false><<<gD, 256, 0, stream>>>(G, A, g2_relT, g2_rootT, g2_rel_b, A); // A=h2
    mlp_face_kernel<<<gM, 256, 0, stream>>>(hv, mf_w0, mf_b0, mf_w1T, mf_b1, G);  // G=ff
    layer_kernel<true,  true ><<<gD, 256, 0, stream>>>(G, A, s2w0loT, s2w0hiT, s2_b0, G);
    layer_final_kernel<<<gS, 256, 0, stream>>>(G, s2_w1T, s2_b1, s2_w2, s2_b2,
                                               (float*)d_out);
  } else {
    mlp_face_kernel<<<gM, 256, 0, stream>>>(hv, mf_w0, mf_b0, mf_w1T, mf_b1, A);
    (void)hipMemsetAsync(G, 0, ACT_BYTES, stream);
    scatter_kernel<<<4096, 256, 0, stream>>>(A, ei, (__half2*)G);
    layer_kernel<true,  true ><<<gD, 256, 0, stream>>>(G, A, g1_relT, g1_rootT, g1_rel_b, A);
    layer_kernel<false, true ><<<gS, 256, 0, stream>>>(A, nullptr, s1_w0T, nullptr, s1_b0, A);
    layer_kernel<false, true ><<<gS, 256, 0, stream>>>(A, nullptr, s1_w1T, nullptr, s1_b1, A);
    layer_kernel<false, true ><<<gS, 256, 0, stream>>>(A, nullptr, s1_w2T, nullptr, s1_b2, A);
    (void)hipMemsetAsync(G, 0, ACT_BYTES, stream);
    scatter_kernel<<<4096, 256, 0, stream>>>(A, ei, (__half2*)G);
    layer_kernel<true,  false><<<gD, 256, 0, stream>>>(G, A, g2_relT, g2_rootT, g2_rel_b, A);
    mlp_face_kernel<<<gM, 256, 0, stream>>>(hv, mf_w0, mf_b0, mf_w1T, mf_b1, G);
    layer_kernel<true,  true ><<<gD, 256, 0, stream>>>(G, A, s2w0loT, s2w0hiT, s2_b0, G);
    layer_final_kernel<<<gS, 256, 0, stream>>>(G, s2_w1T, s2_b1, s2_w2, s2_b2,
                                               (float*)d_out);
  }
}